// Round 1
// 815.806 us; speedup vs baseline: 1.1349x; 1.1349x over previous
//
#include <hip/hip_runtime.h>

#define FP8_MAX 448.0f

typedef float f32x16 __attribute__((ext_vector_type(16)));
typedef int v8i __attribute__((ext_vector_type(8)));
typedef int v4i __attribute__((ext_vector_type(4)));

// ---- async global->LDS, 16B per lane (m97/m193) ----
__device__ __forceinline__ void load_lds16(const void* g, void* l) {
  __builtin_amdgcn_global_load_lds(
      (__attribute__((address_space(1))) void*)g,
      (__attribute__((address_space(3))) void*)l,
      16, 0, 0);
}

// ---- zero the two absmax slots (d_ws is poisoned 0xAA each call) ----
__global__ void init_scales_kernel(unsigned* s) {
  s[0] = 0u;
  s[1] = 0u;
}

// ---- per-tensor absmax: float4 grid-stride + wave64 reduce + atomicMax ----
__global__ void absmax_kernel(const float4* __restrict__ in,
                              unsigned* __restrict__ out, int n4) {
  float m = 0.f;
  int stride = gridDim.x * blockDim.x;
  for (int i = blockIdx.x * blockDim.x + threadIdx.x; i < n4; i += stride) {
    float4 v = in[i];
    m = fmaxf(m, fmaxf(fmaxf(fabsf(v.x), fabsf(v.y)),
                       fmaxf(fabsf(v.z), fabsf(v.w))));
  }
#pragma unroll
  for (int off = 32; off > 0; off >>= 1)
    m = fmaxf(m, __shfl_down(m, off, 64));
  __shared__ float sred[4];
  int lane = threadIdx.x & 63;
  int wid = threadIdx.x >> 6;
  if (lane == 0) sred[wid] = m;
  __syncthreads();
  if (threadIdx.x == 0) {
    m = fmaxf(fmaxf(sred[0], sred[1]), fmaxf(sred[2], sred[3]));
    atomicMax(out, __float_as_uint(m));  // positive floats: uint order == float order
  }
}

// ---- quantize fp32 -> fp8 e4m3, grid-stride float4 in -> dword out ----
// (grid-stride @4096 blocks: 65536 tiny blocks paid CP dispatch overhead)
__global__ void quant_x_kernel(const float4* __restrict__ x,
                               unsigned* __restrict__ xq,
                               const unsigned* __restrict__ sc, int n4) {
  float s = FP8_MAX / __uint_as_float(sc[0]);
  int stride = gridDim.x * blockDim.x;
  for (int t = blockIdx.x * blockDim.x + threadIdx.x; t < n4; t += stride) {
    float4 v = x[t];
    float q0 = fminf(fmaxf(v.x * s, -FP8_MAX), FP8_MAX);
    float q1 = fminf(fmaxf(v.y * s, -FP8_MAX), FP8_MAX);
    float q2 = fminf(fmaxf(v.z * s, -FP8_MAX), FP8_MAX);
    float q3 = fminf(fmaxf(v.w * s, -FP8_MAX), FP8_MAX);
    int p = __builtin_amdgcn_cvt_pk_fp8_f32(q0, q1, 0, false);
    p = __builtin_amdgcn_cvt_pk_fp8_f32(q2, q3, p, true);
    xq[t] = (unsigned)p;
  }
}

// ---- transpose+quantize w [K,N] fp32 -> wq_t [N,K] fp8, 64x64 LDS tiles ----
__global__ void quant_wt_kernel(const float* __restrict__ w,
                                unsigned char* __restrict__ wq,
                                const unsigned* __restrict__ sc, int K, int N) {
  __shared__ float tile[64][65];  // +1 pad: transposed reads land 2-way max
  float s = FP8_MAX / __uint_as_float(sc[1]);
  int nt = blockIdx.x * 64;
  int kt = blockIdx.y * 64;
#pragma unroll
  for (int it = 0; it < 4; ++it) {
    int idx = threadIdx.x + it * 256;
    int r = idx >> 4;        // k row within tile
    int c = (idx & 15) * 4;  // n col within tile
    float4 v = *(const float4*)&w[(size_t)(kt + r) * N + nt + c];
    tile[r][c + 0] = v.x; tile[r][c + 1] = v.y;
    tile[r][c + 2] = v.z; tile[r][c + 3] = v.w;
  }
  __syncthreads();
  int n = threadIdx.x >> 2;          // 0..63
  int k0 = (threadIdx.x & 3) * 16;   // 0,16,32,48
  unsigned r4[4];
#pragma unroll
  for (int q = 0; q < 4; ++q) {
    float a0 = fminf(fmaxf(tile[k0 + q * 4 + 0][n] * s, -FP8_MAX), FP8_MAX);
    float a1 = fminf(fmaxf(tile[k0 + q * 4 + 1][n] * s, -FP8_MAX), FP8_MAX);
    float a2 = fminf(fmaxf(tile[k0 + q * 4 + 2][n] * s, -FP8_MAX), FP8_MAX);
    float a3 = fminf(fmaxf(tile[k0 + q * 4 + 3][n] * s, -FP8_MAX), FP8_MAX);
    int p = __builtin_amdgcn_cvt_pk_fp8_f32(a0, a1, 0, false);
    p = __builtin_amdgcn_cvt_pk_fp8_f32(a2, a3, p, true);
    r4[q] = (unsigned)p;
  }
  uint4 o;
  o.x = r4[0]; o.y = r4[1]; o.z = r4[2]; o.w = r4[3];
  *(uint4*)&wq[(size_t)(nt + n) * K + kt + k0] = o;
}

// ===========================================================================
// MX-scaled fp8 GEMM, 8-phase 256x256 template (m201 port to fp8):
//   C[M,N] = Aq[M,K] . Bq[N,K]^T, mfma_scale_f32_32x32x64_f8f6f4, scale=0x7f.
//   BM=BN=256, BK=128 bytes, 512 thr = 8 waves (2M x 4N), per-wave 128x64
//   as 4x2 tiles of 32x32.  LDS 128 KiB = 2 dbuf x (A 32K + B 32K).
//
// LDS layout + swizzle (T2): rows of 128B = 8 x 16B chunks; stored chunk
//   c' = c ^ (row&7).  Staged via global_load_lds with PRE-SWIZZLED global
//   source (LDS dest must stay linear, m104/m173); frag ds_read_b128 applies
//   the same XOR -> every consecutive-8-lane group covers all 8 slots
//   (conflict-free; the old f(row)=row&3 left ~16 lanes/bank, 1e8 conflicts).
//
// Staging rounds per K-tile (8 x 1KB/wave): r0=A[rows 0-63], r1=A[128-191],
//   r2..r5 = B interleaved (round ri covers n in {q16: ri*16+(0..15) per 64}),
//   r6=A[64-127], r7=A[192-255].  Phase p issues 2 rounds of tile kt+1.
//
// Phase schedule per K-tile (quadrants mh x nh), counted vmcnt (T3/T4):
//   P0: read A(mh0) 8x + B(nt0) 4x | stage r0,r1 | BAR lgkm0 prio MFMA prio |
//       vmcnt(4) BAR      <- drains S(kt) r4,r5 needed by P1
//   P1: read B(nt1) 4x            | stage r2,r3 | ... | vmcnt(4) BAR  <- r6,r7 for P2
//   P2: read A(mh1) 8x            | stage r4,r5 | ... | BAR
//   P3: (regs only)               | stage r6,r7 | ... | vmcnt(4) BAR  <- S(kt+1) r0..r3 for next P0
//   Invariant: 4..8 loads in flight, never vmcnt(0) in the loop.  Last tile
//   stages a dummy (tile 0, dead buffer) to keep counts uniform.
// NOTE: no VGPR spills allowed (scratch ops would corrupt vmcnt counting) ->
//   launch_bounds(512,2) caps at 256 VGPR; design uses ~215.
// ===========================================================================

#define BAR() asm volatile("s_barrier" ::: "memory")
#define WAIT_LGKM0()                                        \
  do {                                                      \
    asm volatile("s_waitcnt lgkmcnt(0)" ::: "memory");      \
    __builtin_amdgcn_sched_barrier(0);                      \
  } while (0)
#define WAIT_VM(N)                                          \
  do {                                                      \
    asm volatile("s_waitcnt vmcnt(" #N ")" ::: "memory");   \
    __builtin_amdgcn_sched_barrier(0);                      \
  } while (0)

#define MM(d, a, b)                                              \
  d = __builtin_amdgcn_mfma_scale_f32_32x32x64_f8f6f4(           \
      (a), (b), (d), 0, 0, 0, 0x7f7f7f7f, 0, 0x7f7f7f7f)

__device__ __forceinline__ v8i rd_frag(const unsigned char* p, int b0, int b1) {
  v4i lo = *(const v4i*)(p + b0);
  v4i hi = *(const v4i*)(p + b1);
  return __builtin_shufflevector(lo, hi, 0, 1, 2, 3, 4, 5, 6, 7);
}

// one K-tile: read bufs RA/RB, stage tile at byte KOFF into WA/WB
#define KTILE(RA, RB, WA, WB, KOFF)                                            \
  {                                                                            \
    /* ---- P0: mh=0, nt=0 ---- */                                             \
    af00 = rd_frag((RA) + raB[0], (khx + 0) ^ fxA[0], (khx + 16) ^ fxA[0]);    \
    af01 = rd_frag((RA) + raB[0], (khx + 64) ^ fxA[0], (khx + 80) ^ fxA[0]);   \
    af10 = rd_frag((RA) + raB[1], (khx + 0) ^ fxA[1], (khx + 16) ^ fxA[1]);    \
    af11 = rd_frag((RA) + raB[1], (khx + 64) ^ fxA[1], (khx + 80) ^ fxA[1]);   \
    bf00 = rd_frag((RB) + qB[0], (khx + 0) ^ fxB, (khx + 16) ^ fxB);           \
    bf01 = rd_frag((RB) + qB[0], (khx + 64) ^ fxB, (khx + 80) ^ fxB);          \
    load_lds16(gA0 + 0 * kA + (KOFF), (WA) + 0 * 8192 + ldst);                 \
    load_lds16(gA0 + 2 * kA + (KOFF), (WA) + 2 * 8192 + ldst);                 \
    BAR();                                                                     \
    WAIT_LGKM0();                                                              \
    __builtin_amdgcn_s_setprio(1);                                             \
    MM(acc00, af00, bf00); MM(acc10, af10, bf00);                              \
    MM(acc00, af01, bf01); MM(acc10, af11, bf01);                              \
    __builtin_amdgcn_s_setprio(0);                                             \
    WAIT_VM(4);                                                                \
    BAR();                                                                     \
    /* ---- P1: mh=0, nt=1 ---- */                                             \
    bf10 = rd_frag((RB) + qB[1], (khx + 0) ^ fxB, (khx + 16) ^ fxB);           \
    bf11 = rd_frag((RB) + qB[1], (khx + 64) ^ fxB, (khx + 80) ^ fxB);          \
    load_lds16(gB0 + 0 * kB + (KOFF), (WB) + 0 * 8192 + ldst);                 \
    load_lds16(gB0 + 1 * kB + (KOFF), (WB) + 1 * 8192 + ldst);                 \
    BAR();                                                                     \
    WAIT_LGKM0();                                                              \
    __builtin_amdgcn_s_setprio(1);                                             \
    MM(acc01, af00, bf10); MM(acc11, af10, bf10);                              \
    MM(acc01, af01, bf11); MM(acc11, af11, bf11);                              \
    __builtin_amdgcn_s_setprio(0);                                             \
    WAIT_VM(4);                                                                \
    BAR();                                                                     \
    /* ---- P2: mh=1, nt=0 ---- */                                             \
    af00 = rd_frag((RA) + raB[2], (khx + 0) ^ fxA[2], (khx + 16) ^ fxA[2]);    \
    af01 = rd_frag((RA) + raB[2], (khx + 64) ^ fxA[2], (khx + 80) ^ fxA[2]);   \
    af10 = rd_frag((RA) + raB[3], (khx + 0) ^ fxA[3], (khx + 16) ^ fxA[3]);    \
    af11 = rd_frag((RA) + raB[3], (khx + 64) ^ fxA[3], (khx + 80) ^ fxA[3]);   \
    load_lds16(gB0 + 2 * kB + (KOFF), (WB) + 2 * 8192 + ldst);                 \
    load_lds16(gB0 + 3 * kB + (KOFF), (WB) + 3 * 8192 + ldst);                 \
    BAR();                                                                     \
    WAIT_LGKM0();                                                              \
    __builtin_amdgcn_s_setprio(1);                                             \
    MM(acc20, af00, bf00); MM(acc30, af10, bf00);                              \
    MM(acc20, af01, bf01); MM(acc30, af11, bf01);                              \
    __builtin_amdgcn_s_setprio(0);                                             \
    BAR();                                                                     \
    /* ---- P3: mh=1, nt=1 (register-only reads) ---- */                       \
    load_lds16(gA0 + 1 * kA + (KOFF), (WA) + 1 * 8192 + ldst);                 \
    load_lds16(gA0 + 3 * kA + (KOFF), (WA) + 3 * 8192 + ldst);                 \
    BAR();                                                                     \
    __builtin_amdgcn_s_setprio(1);                                             \
    MM(acc21, af00, bf10); MM(acc31, af10, bf10);                              \
    MM(acc21, af01, bf11); MM(acc31, af11, bf11);                              \
    __builtin_amdgcn_s_setprio(0);                                             \
    WAIT_VM(4);                                                                \
    BAR();                                                                     \
  }

__global__ __launch_bounds__(512, 2) void gemm_fp8_kernel(
    const unsigned char* __restrict__ A,   // [M,K] fp8
    const unsigned char* __restrict__ B,   // [N,K] fp8
    float* __restrict__ C,                 // [M,N] fp32
    const unsigned* __restrict__ am, int Mi, int Ni, int Ki) {
  __shared__ __align__(16) unsigned char sm[131072];
  unsigned char* const smA0 = sm;
  unsigned char* const smA1 = sm + 32768;
  unsigned char* const smB0 = sm + 65536;
  unsigned char* const smB1 = sm + 98304;

  const int t = threadIdx.x;
  const int lane = t & 63;
  const int wave = t >> 6;
  const int wm = wave >> 2;  // 0..1
  const int wn = wave & 3;   // 0..3
  const int l31 = lane & 31;
  const int kh = lane >> 5;
  const int khx = kh * 32;

  // bijective XCD swizzle (nwg=1024, %8==0)
  const int bid = blockIdx.y * gridDim.x + blockIdx.x;
  const int swz = (bid & 7) * 128 + (bid >> 3);
  const int m0 = (swz >> 4) * 256;
  const int n0 = (swz & 15) * 256;

  // ---- staging addresses (pre-swizzled global source, linear LDS dest) ----
  const int rt = t >> 3;  // row within 64-row round
  const int cst = ((t & 7) ^ (rt & 7)) * 16;
  const unsigned char* gA0 = A + (size_t)(m0 + rt) * Ki + cst;
  const unsigned char* gB0 =
      B + (size_t)(n0 + (rt >> 4) * 64 + (rt & 15)) * Ki + cst;
  const size_t kA = (size_t)Ki * 64;  // A round stride (64 rows)
  const size_t kB = (size_t)Ki * 16;  // B round stride (16 n per 64-block)
  const int ldst = t * 16;

  // ---- frag read bases ----
  int raB[4], fxA[4];
#pragma unroll
  for (int mt = 0; mt < 4; ++mt) {
    int ra = wm * 128 + mt * 32 + l31;
    raB[mt] = ra * 128;
    fxA[mt] = (ra & 7) * 16;
  }
  const int q = wn * 16 + (l31 & 15);
  const int fxB = (q & 7) * 16;
  int qB[2];
#pragma unroll
  for (int nt = 0; nt < 2; ++nt)
    qB[nt] = (nt * 2 + (l31 >> 4)) * 8192 + q * 128;

  f32x16 zero;
#pragma unroll
  for (int r = 0; r < 16; ++r) zero[r] = 0.f;
  f32x16 acc00 = zero, acc01 = zero, acc10 = zero, acc11 = zero;
  f32x16 acc20 = zero, acc21 = zero, acc30 = zero, acc31 = zero;
  v8i af00, af01, af10, af11, bf00, bf01, bf10, bf11;

  // ---- prologue: stage K-tile 0 into buf0, round order r0..r7 ----
  load_lds16(gA0 + 0 * kA, smA0 + 0 * 8192 + ldst);
  load_lds16(gA0 + 2 * kA, smA0 + 2 * 8192 + ldst);
  load_lds16(gB0 + 0 * kB, smB0 + 0 * 8192 + ldst);
  load_lds16(gB0 + 1 * kB, smB0 + 1 * 8192 + ldst);
  load_lds16(gB0 + 2 * kB, smB0 + 2 * 8192 + ldst);
  load_lds16(gB0 + 3 * kB, smB0 + 3 * 8192 + ldst);
  load_lds16(gA0 + 1 * kA, smA0 + 1 * 8192 + ldst);
  load_lds16(gA0 + 3 * kA, smA0 + 3 * 8192 + ldst);
  WAIT_VM(4);  // r0..r3 landed (needed by first P0)
  BAR();

  const int KT = Ki >> 7;  // 128B K-tiles
  for (int kt = 0; kt < KT; kt += 2) {
    const size_t ko1 = (size_t)(kt + 1) * 128;
    const size_t ko2 = (kt + 2 < KT) ? (size_t)(kt + 2) * 128 : 0;  // dummy wrap
    KTILE(smA0, smB0, smA1, smB1, ko1);
    KTILE(smA1, smB1, smA0, smB0, ko2);
  }
  asm volatile("s_waitcnt vmcnt(0)" ::: "memory");  // drain dummy stages

  // ---- epilogue: dequant y/(sx*sw) and store (32x32 C/D layout, m74/m101) --
  float ax = __uint_as_float(am[0]);
  float aw = __uint_as_float(am[1]);
  float sxs = FP8_MAX / ax;
  float sws = FP8_MAX / aw;
  float inv = 1.f / (sxs * sws);
  const int colb = n0 + wn * 64 + l31;

#define STORE(AV, MT, NT)                                                     \
  _Pragma("unroll") for (int r = 0; r < 16; ++r) {                            \
    int row = m0 + wm * 128 + (MT) * 32 + (r & 3) + 8 * (r >> 2) + 4 * kh;    \
    C[(size_t)row * Ni + colb + (NT) * 32] = AV[r] * inv;                     \
  }
  STORE(acc00, 0, 0); STORE(acc01, 0, 1);
  STORE(acc10, 1, 0); STORE(acc11, 1, 1);
  STORE(acc20, 2, 0); STORE(acc21, 2, 1);
  STORE(acc30, 3, 0); STORE(acc31, 3, 1);
#undef STORE
  (void)Mi;
}

extern "C" void kernel_launch(void* const* d_in, const int* in_sizes, int n_in,
                              void* d_out, int out_size, void* d_ws,
                              size_t ws_size, hipStream_t stream) {
  const int M = 16384, K = 4096, N = 4096;
  const float* x = (const float*)d_in[0];  // [M,K]
  const float* w = (const float*)d_in[1];  // [K,N]
  float* out = (float*)d_out;              // [M,N]

  unsigned* scales = (unsigned*)d_ws;                 // [0]=absmax_x [1]=absmax_w
  unsigned char* xq = (unsigned char*)d_ws + 256;     // [M,K] fp8 (64 MiB)
  unsigned char* wq = xq + (size_t)M * K;             // [N,K] fp8 (16 MiB)

  init_scales_kernel<<<1, 1, 0, stream>>>(scales);
  absmax_kernel<<<8192, 256, 0, stream>>>((const float4*)x, scales + 0,
                                          M * K / 4);
  absmax_kernel<<<2048, 256, 0, stream>>>((const float4*)w, scales + 1,
                                          K * N / 4);
  quant_x_kernel<<<4096, 256, 0, stream>>>((const float4*)x, (unsigned*)xq,
                                           scales, M * K / 4);
  quant_wt_kernel<<<dim3(N / 64, K / 64), 256, 0, stream>>>(w, wq, scales, K,
                                                            N);
  gemm_fp8_kernel<<<dim3(N / 256, M / 256), 512, 0, stream>>>(xq, wq, out,
                                                              scales, M, N, K);
}